// Round 7
// baseline (830.608 us; speedup 1.0000x reference)
//
#include <hip/hip_runtime.h>
#include <hip/hip_bf16.h>
#include <math.h>

// Problem constants (match reference setup_inputs)
#define N_NODES 100000
#define N_EDGES 1600000
#define F 128

// ---------------- ws layout (bytes) ----------------
// deg    : int[100000]      @ 0         (400000)
// norm   : float[100000]    @ 400000    (400000)
// offs   : int[100001]      @ 800000    (400004)
// cursor : int[100000]      @ 1200016   (400000)
// ssrc   : int[1600000]     @ 1600016   (6400000)
// bsum   : int[256]         @ 8000016   (1024)
// featn  : float[100000*128]@ 8001536   (51200000)
// wT_ih  : float[128*384]   @ 59201536  (196608)
// wT_hh  : float[128*384]   @ 59398144  (196608)

#define WS_FEATN_OFF 8001536
#define WS_WTI_OFF   59201536
#define WS_WTH_OFF   59398144
#define WS_NEED_FULL (WS_WTH_OFF + 196608)

// ---------- 1. degree count ----------
__global__ __launch_bounds__(256) void k_degree(const int* __restrict__ dst,
                                                int* __restrict__ deg) {
    int i = blockIdx.x * 256 + threadIdx.x;
    if (i < N_EDGES) atomicAdd(&deg[dst[i]], 1);
}

// ---------- 2. scan (3 kernels); scan3 also emits norm + zeroes cursor ----------
#define SCAN_B 512
#define SCAN_NB 196  // ceil(100000/512)

__global__ __launch_bounds__(SCAN_B) void k_scan1(const int* __restrict__ deg,
                                                  int* __restrict__ bsum) {
    __shared__ int s[SCAN_B];
    int t = threadIdx.x;
    int i = blockIdx.x * SCAN_B + t;
    s[t] = (i < N_NODES) ? deg[i] : 0;
    __syncthreads();
    for (int o = SCAN_B / 2; o > 0; o >>= 1) {
        if (t < o) s[t] += s[t + o];
        __syncthreads();
    }
    if (t == 0) bsum[blockIdx.x] = s[0];
}

__global__ __launch_bounds__(256) void k_scan2(int* __restrict__ bsum) {
    __shared__ int s[256];
    int t = threadIdx.x;
    int v = (t < SCAN_NB) ? bsum[t] : 0;
    s[t] = v;
    __syncthreads();
    for (int o = 1; o < 256; o <<= 1) {
        int x = (t >= o) ? s[t - o] : 0;
        __syncthreads();
        s[t] += x;
        __syncthreads();
    }
    if (t < SCAN_NB) bsum[t] = (t == 0) ? 0 : s[t - 1];  // exclusive scan of block sums
}

__global__ __launch_bounds__(SCAN_B) void k_scan3(const int* __restrict__ deg,
                                                  const int* __restrict__ bsum,
                                                  int* __restrict__ offs,
                                                  float* __restrict__ norm,
                                                  int* __restrict__ cursor) {
    __shared__ int s[SCAN_B];
    int t = threadIdx.x;
    int i = blockIdx.x * SCAN_B + t;
    int v = (i < N_NODES) ? deg[i] : 0;
    s[t] = v;
    __syncthreads();
    for (int o = 1; o < SCAN_B; o <<= 1) {
        int x = (t >= o) ? s[t - o] : 0;
        __syncthreads();
        s[t] += x;
        __syncthreads();
    }
    if (i < N_NODES) {
        offs[i] = bsum[blockIdx.x] + s[t] - v;  // exclusive
        norm[i] = rsqrtf(fmaxf((float)v, 1.0f));
        cursor[i] = 0;                           // zero for k_fill (replaces memset)
    }
    if (blockIdx.x == 0 && t == 0) offs[N_NODES] = N_EDGES;
}

// ---------- 3. CSR bucket fill ----------
__global__ __launch_bounds__(256) void k_fill(const int* __restrict__ src,
                                              const int* __restrict__ dst,
                                              const int* __restrict__ offs,
                                              int* __restrict__ cursor,
                                              int* __restrict__ ssrc) {
    int i = blockIdx.x * 256 + threadIdx.x;
    if (i < N_EDGES) {
        int d = dst[i];
        int p = atomicAdd(&cursor[d], 1);
        ssrc[offs[d] + p] = src[i];
    }
}

// ---------- 4. featn = feat * norm[row] (float4 elementwise) ----------
__global__ __launch_bounds__(256) void k_featn(const float* __restrict__ feat,
                                               const float* __restrict__ norm,
                                               float* __restrict__ featn) {
    int idx = blockIdx.x * 256 + threadIdx.x;  // float4 index; F/4=32 per row
    int row = idx >> 5;
    float nv = norm[row];
    float4 v = ((const float4*)feat)[idx];
    v.x *= nv; v.y *= nv; v.z *= nv; v.w *= nv;
    ((float4*)featn)[idx] = v;
}

// ---------- 5. weight transpose [384][128] -> [128][384], both matrices ----------
__global__ __launch_bounds__(256) void k_wt(const float* __restrict__ w_ih,
                                            const float* __restrict__ w_hh,
                                            float* __restrict__ wT_ih,
                                            float* __restrict__ wT_hh) {
    __shared__ float tile[32][33];  // +1 pad: conflict-free transpose
    int b = blockIdx.x;             // 0..95: first 48 = w_ih, last 48 = w_hh
    const float* w = (b < 48) ? w_ih : w_hh;
    float* wT      = (b < 48) ? wT_ih : wT_hh;
    int bb = (b < 48) ? b : b - 48;
    int rt = bb >> 2, ct = bb & 3;  // 12 row-tiles x 4 col-tiles
    int r0 = rt * 32, c0 = ct * 32;
    int tr = threadIdx.x >> 5, tc = threadIdx.x & 31;  // 8 x 32
#pragma unroll
    for (int i = 0; i < 32; i += 8)
        tile[tr + i][tc] = w[(r0 + tr + i) * 128 + c0 + tc];  // coalesced read
    __syncthreads();
#pragma unroll
    for (int i = 0; i < 32; i += 8)
        wT[(c0 + tr + i) * 384 + r0 + tc] = tile[tc][tr + i];  // coalesced write
}

// ---------- 6. fused gather + rst-GEMM + GRU ----------
// ROWS=8, 4 rows/thread, fused r/z accumulator chains (16 live accs -> no spill).
// PRE=true : `fsrc` = precomputed featn; `wih_`/`whh_` = TRANSPOSED weights [128][384]
// PRE=false: `fsrc` = raw feat (norm applied inline); `wih_`/`whh_` = raw [384][128]
#define ROWS 8
template <bool PRE>
__global__ __launch_bounds__(256, 4) void k_fused(
    const float* __restrict__ fsrc, const float* __restrict__ norm,
    const int* __restrict__ offs, const int* __restrict__ ssrc,
    const float* __restrict__ W, const float* __restrict__ bias,
    const float* __restrict__ wih_, const float* __restrict__ whh_,
    const float* __restrict__ b_ih, const float* __restrict__ b_hh,
    float* __restrict__ out) {
    __shared__ float sagg[ROWS][F];
    __shared__ float sfeat[ROWS][F];
    __shared__ float srst[ROWS][F];
    __shared__ float snorm[ROWS];

    int t = threadIdx.x;
    int row0 = blockIdx.x * ROWS;

    if (t < ROWS) snorm[t] = norm[row0 + t];
    // stage featn tile for the dst rows (coalesced float4; 256 float4 = 1/thread)
    {
        int r = t >> 5, c = t & 31;
        float4 f = ((const float4*)(fsrc + (size_t)(row0 + r) * F))[c];
        if (!PRE) {
            float nv = norm[row0 + r];
            f.x *= nv; f.y *= nv; f.z *= nv; f.w *= nv;
        }
        ((float4*)&sfeat[r][0])[c] = f;
    }

    // ---- Phase A: gather-sum featn[src] rows into sagg ----
    // one wave per node (2 local nodes per wave); half-wave per edge, float4/lane;
    // 8 edges per main-loop iter -> 4 independent row-loads in flight per lane
    int wave = t >> 6, lane = t & 63;
    int hf = lane >> 5, sub = lane & 31;
    for (int ln = wave; ln < ROWS; ln += 4) {
        int node = row0 + ln;
        int beg = offs[node], end = offs[node + 1];
        float4 acc = make_float4(0.f, 0.f, 0.f, 0.f);
        int e = beg;
        for (; e + 7 < end; e += 8) {
            int s0 = ssrc[e + 0 + hf];
            int s1 = ssrc[e + 2 + hf];
            int s2 = ssrc[e + 4 + hf];
            int s3 = ssrc[e + 6 + hf];
            float4 v0 = *(const float4*)(fsrc + (size_t)s0 * F + sub * 4);
            float4 v1 = *(const float4*)(fsrc + (size_t)s1 * F + sub * 4);
            float4 v2 = *(const float4*)(fsrc + (size_t)s2 * F + sub * 4);
            float4 v3 = *(const float4*)(fsrc + (size_t)s3 * F + sub * 4);
            if (PRE) {
                acc.x += (v0.x + v1.x) + (v2.x + v3.x);
                acc.y += (v0.y + v1.y) + (v2.y + v3.y);
                acc.z += (v0.z + v1.z) + (v2.z + v3.z);
                acc.w += (v0.w + v1.w) + (v2.w + v3.w);
            } else {
                float n0 = norm[s0], n1 = norm[s1], n2 = norm[s2], n3 = norm[s3];
                acc.x = fmaf(v0.x, n0, acc.x); acc.y = fmaf(v0.y, n0, acc.y);
                acc.z = fmaf(v0.z, n0, acc.z); acc.w = fmaf(v0.w, n0, acc.w);
                acc.x = fmaf(v1.x, n1, acc.x); acc.y = fmaf(v1.y, n1, acc.y);
                acc.z = fmaf(v1.z, n1, acc.z); acc.w = fmaf(v1.w, n1, acc.w);
                acc.x = fmaf(v2.x, n2, acc.x); acc.y = fmaf(v2.y, n2, acc.y);
                acc.z = fmaf(v2.z, n2, acc.z); acc.w = fmaf(v2.w, n2, acc.w);
                acc.x = fmaf(v3.x, n3, acc.x); acc.y = fmaf(v3.y, n3, acc.y);
                acc.z = fmaf(v3.z, n3, acc.z); acc.w = fmaf(v3.w, n3, acc.w);
            }
        }
        for (; e < end; e += 2) {  // remainder 0..7 edges (odd handled by guard)
            int edge = e + hf;
            if (edge < end) {
                int s0 = ssrc[edge];
                float4 v0 = *(const float4*)(fsrc + (size_t)s0 * F + sub * 4);
                float n0 = PRE ? 1.0f : norm[s0];
                acc.x = fmaf(v0.x, n0, acc.x); acc.y = fmaf(v0.y, n0, acc.y);
                acc.z = fmaf(v0.z, n0, acc.z); acc.w = fmaf(v0.w, n0, acc.w);
            }
        }
        acc.x += __shfl_xor(acc.x, 32, 64);
        acc.y += __shfl_xor(acc.y, 32, 64);
        acc.z += __shfl_xor(acc.z, 32, 64);
        acc.w += __shfl_xor(acc.w, 32, 64);
        if (hf == 0) *(float4*)&sagg[ln][sub * 4] = acc;
    }
    __syncthreads();

    // ---- Phase B: srst = (sagg @ W) * norm + bias (4 rows/thread) ----
    int j = t & 127;
    int rg = (t >> 7) * 4;  // 0 or 4
    {
        float acc[4] = {0, 0, 0, 0};
        for (int k = 0; k < F; k += 4) {
            float w0 = W[(k + 0) * F + j];  // coalesced across lanes
            float w1 = W[(k + 1) * F + j];
            float w2 = W[(k + 2) * F + j];
            float w3 = W[(k + 3) * F + j];
#pragma unroll
            for (int r = 0; r < 4; ++r) {
                float4 a = *(const float4*)&sagg[rg + r][k];  // LDS broadcast
                acc[r] = fmaf(a.x, w0, acc[r]);
                acc[r] = fmaf(a.y, w1, acc[r]);
                acc[r] = fmaf(a.z, w2, acc[r]);
                acc[r] = fmaf(a.w, w3, acc[r]);
            }
        }
        float bj = bias[j];
#pragma unroll
        for (int r = 0; r < 4; ++r) {
            srst[rg + r][j] = acc[r] * snorm[rg + r] + bj;
        }
    }
    __syncthreads();

    // ---- Phase C: GRU gates, fused r/z chains (16 live accumulators) ----
    float accr[4] = {0, 0, 0, 0};   // i_r + h_r
    float accz[4] = {0, 0, 0, 0};   // i_z + h_z
    float accin[4] = {0, 0, 0, 0};  // i_n
    float acchn[4] = {0, 0, 0, 0};  // h_n

    if (PRE) {
        // transposed weights: wT[k*384 + (gate*128 + j)] — lane-coalesced
        for (int k = 0; k < F; k += 4) {
            float wir[4], wiz[4], win[4], whr[4], whz[4], whn[4];
#pragma unroll
            for (int kk = 0; kk < 4; ++kk) {
                const float* wik = wih_ + (size_t)(k + kk) * 384 + j;
                const float* whk = whh_ + (size_t)(k + kk) * 384 + j;
                wir[kk] = wik[0]; wiz[kk] = wik[128]; win[kk] = wik[256];
                whr[kk] = whk[0]; whz[kk] = whk[128]; whn[kk] = whk[256];
            }
#pragma unroll
            for (int r = 0; r < 4; ++r) {
                float4 a = *(const float4*)&sfeat[rg + r][k];  // LDS broadcast
                float4 h = *(const float4*)&srst[rg + r][k];
                accr[r] = fmaf(a.x, wir[0], accr[r]); accr[r] = fmaf(h.x, whr[0], accr[r]);
                accr[r] = fmaf(a.y, wir[1], accr[r]); accr[r] = fmaf(h.y, whr[1], accr[r]);
                accr[r] = fmaf(a.z, wir[2], accr[r]); accr[r] = fmaf(h.z, whr[2], accr[r]);
                accr[r] = fmaf(a.w, wir[3], accr[r]); accr[r] = fmaf(h.w, whr[3], accr[r]);
                accz[r] = fmaf(a.x, wiz[0], accz[r]); accz[r] = fmaf(h.x, whz[0], accz[r]);
                accz[r] = fmaf(a.y, wiz[1], accz[r]); accz[r] = fmaf(h.y, whz[1], accz[r]);
                accz[r] = fmaf(a.z, wiz[2], accz[r]); accz[r] = fmaf(h.z, whz[2], accz[r]);
                accz[r] = fmaf(a.w, wiz[3], accz[r]); accz[r] = fmaf(h.w, whz[3], accz[r]);
                accin[r] = fmaf(a.x, win[0], accin[r]); accin[r] = fmaf(a.y, win[1], accin[r]);
                accin[r] = fmaf(a.z, win[2], accin[r]); accin[r] = fmaf(a.w, win[3], accin[r]);
                acchn[r] = fmaf(h.x, whn[0], acchn[r]); acchn[r] = fmaf(h.y, whn[1], acchn[r]);
                acchn[r] = fmaf(h.z, whn[2], acchn[r]); acchn[r] = fmaf(h.w, whn[3], acchn[r]);
            }
        }
    } else {
        // fallback: raw [384][128] row-major weight rows (uncoalesced but correct)
        const float* wirp = wih_ + (size_t)(j + 0) * F;
        const float* wizp = wih_ + (size_t)(j + 128) * F;
        const float* winp = wih_ + (size_t)(j + 256) * F;
        const float* whrp = whh_ + (size_t)(j + 0) * F;
        const float* whzp = whh_ + (size_t)(j + 128) * F;
        const float* whnp = whh_ + (size_t)(j + 256) * F;
        for (int k = 0; k < F; k += 4) {
            float4 bir = *(const float4*)(wirp + k);
            float4 biz = *(const float4*)(wizp + k);
            float4 bin = *(const float4*)(winp + k);
            float4 bhr = *(const float4*)(whrp + k);
            float4 bhz = *(const float4*)(whzp + k);
            float4 bhn = *(const float4*)(whnp + k);
#pragma unroll
            for (int r = 0; r < 4; ++r) {
                float4 a = *(const float4*)&sfeat[rg + r][k];
                float4 h = *(const float4*)&srst[rg + r][k];
                accr[r] = fmaf(a.x, bir.x, accr[r]); accr[r] = fmaf(h.x, bhr.x, accr[r]);
                accr[r] = fmaf(a.y, bir.y, accr[r]); accr[r] = fmaf(h.y, bhr.y, accr[r]);
                accr[r] = fmaf(a.z, bir.z, accr[r]); accr[r] = fmaf(h.z, bhr.z, accr[r]);
                accr[r] = fmaf(a.w, bir.w, accr[r]); accr[r] = fmaf(h.w, bhr.w, accr[r]);
                accz[r] = fmaf(a.x, biz.x, accz[r]); accz[r] = fmaf(h.x, bhz.x, accz[r]);
                accz[r] = fmaf(a.y, biz.y, accz[r]); accz[r] = fmaf(h.y, bhz.y, accz[r]);
                accz[r] = fmaf(a.z, biz.z, accz[r]); accz[r] = fmaf(h.z, bhz.z, accz[r]);
                accz[r] = fmaf(a.w, biz.w, accz[r]); accz[r] = fmaf(h.w, bhz.w, accz[r]);
                accin[r] = fmaf(a.x, bin.x, accin[r]); accin[r] = fmaf(a.y, bin.y, accin[r]);
                accin[r] = fmaf(a.z, bin.z, accin[r]); accin[r] = fmaf(a.w, bin.w, accin[r]);
                acchn[r] = fmaf(h.x, bhn.x, acchn[r]); acchn[r] = fmaf(h.y, bhn.y, acchn[r]);
                acchn[r] = fmaf(h.z, bhn.z, acchn[r]); acchn[r] = fmaf(h.w, bhn.w, acchn[r]);
            }
        }
    }

    float Brz = b_ih[j] + b_hh[j];
    float Bzz = b_ih[j + 128] + b_hh[j + 128];
    float Bin = b_ih[j + 256], Bhn = b_hh[j + 256];
#pragma unroll
    for (int r = 0; r < 4; ++r) {
        int row = row0 + rg + r;
        float rr = 1.0f / (1.0f + __expf(-(accr[r] + Brz)));
        float zz = 1.0f / (1.0f + __expf(-(accz[r] + Bzz)));
        float nn = tanhf(accin[r] + Bin + rr * (acchn[r] + Bhn));
        float rstv = srst[rg + r][j];
        out[(size_t)row * F + j] = (1.0f - zz) * nn + zz * rstv;
    }
}

extern "C" void kernel_launch(void* const* d_in, const int* in_sizes, int n_in,
                              void* d_out, int out_size, void* d_ws, size_t ws_size,
                              hipStream_t stream) {
    const float* feat   = (const float*)d_in[0];
    const float* weight = (const float*)d_in[1];
    const float* bias   = (const float*)d_in[2];
    const float* w_ih   = (const float*)d_in[3];
    const float* w_hh   = (const float*)d_in[4];
    const float* b_ih   = (const float*)d_in[5];
    const float* b_hh   = (const float*)d_in[6];
    const int*   src    = (const int*)d_in[7];
    const int*   dst    = (const int*)d_in[8];
    float* out = (float*)d_out;

    char* ws = (char*)d_ws;
    int*   deg    = (int*)(ws + 0);
    float* norm   = (float*)(ws + 400000);
    int*   offs   = (int*)(ws + 800000);
    int*   cursor = (int*)(ws + 1200016);
    int*   ssrc   = (int*)(ws + 1600016);
    int*   bsum   = (int*)(ws + 8000016);
    float* featn  = (float*)(ws + WS_FEATN_OFF);
    float* wT_ih  = (float*)(ws + WS_WTI_OFF);
    float* wT_hh  = (float*)(ws + WS_WTH_OFF);

    hipMemsetAsync(deg, 0, N_NODES * sizeof(int), stream);

    k_degree<<<(N_EDGES + 255) / 256, 256, 0, stream>>>(dst, deg);
    k_scan1<<<SCAN_NB, SCAN_B, 0, stream>>>(deg, bsum);
    k_scan2<<<1, 256, 0, stream>>>(bsum);
    k_scan3<<<SCAN_NB, SCAN_B, 0, stream>>>(deg, bsum, offs, norm, cursor);
    k_fill<<<(N_EDGES + 255) / 256, 256, 0, stream>>>(src, dst, offs, cursor, ssrc);

    if (ws_size >= WS_NEED_FULL) {
        k_wt<<<96, 256, 0, stream>>>(w_ih, w_hh, wT_ih, wT_hh);
        k_featn<<<(N_NODES * F / 4) / 256, 256, 0, stream>>>(feat, norm, featn);
        k_fused<true><<<N_NODES / ROWS, 256, 0, stream>>>(featn, norm, offs, ssrc,
                                                          weight, bias, wT_ih, wT_hh,
                                                          b_ih, b_hh, out);
    } else {
        k_fused<false><<<N_NODES / ROWS, 256, 0, stream>>>(feat, norm, offs, ssrc,
                                                           weight, bias, w_ih, w_hh,
                                                           b_ih, b_hh, out);
    }
}

// Round 9
// 823.126 us; speedup vs baseline: 1.0091x; 1.0091x over previous
//
#include <hip/hip_runtime.h>
#include <hip/hip_bf16.h>
#include <math.h>

// Problem constants (match reference setup_inputs)
#define N_NODES 100000
#define N_EDGES 1600000
#define F 128

// ---------------- ws layout (bytes) ----------------
// deg    : int[100000]      @ 0         (400000)
// norm   : float[100000]    @ 400000    (400000)
// offs   : int[100001]      @ 800000    (400004)
// cursor : int[100000]      @ 1200016   (400000)
// ssrc   : int[1600000]     @ 1600016   (6400000)
// bsum   : int[256]         @ 8000016   (1024)
// featn  : float[100000*128]@ 8001536   (51200000)
// wPa    : float4[128*128]  @ 59201536  (262144)  {wir,wiz,win,whr}
// wPb    : float2[128*128]  @ 59463680  (131072)  {whz,whn}

#define WS_FEATN_OFF 8001536
#define WS_WPA_OFF   59201536
#define WS_WPB_OFF   59463680
#define WS_NEED_FULL (WS_WPB_OFF + 131072)

// ---------- 1. degree count ----------
__global__ __launch_bounds__(256) void k_degree(const int* __restrict__ dst,
                                                int* __restrict__ deg) {
    int i = blockIdx.x * 256 + threadIdx.x;
    if (i < N_EDGES) atomicAdd(&deg[dst[i]], 1);
}

// ---------- 2. scan (3 kernels); scan3 also emits norm + zeroes cursor ----------
#define SCAN_B 512
#define SCAN_NB 196  // ceil(100000/512)

__global__ __launch_bounds__(SCAN_B) void k_scan1(const int* __restrict__ deg,
                                                  int* __restrict__ bsum) {
    __shared__ int s[SCAN_B];
    int t = threadIdx.x;
    int i = blockIdx.x * SCAN_B + t;
    s[t] = (i < N_NODES) ? deg[i] : 0;
    __syncthreads();
    for (int o = SCAN_B / 2; o > 0; o >>= 1) {
        if (t < o) s[t] += s[t + o];
        __syncthreads();
    }
    if (t == 0) bsum[blockIdx.x] = s[0];
}

__global__ __launch_bounds__(256) void k_scan2(int* __restrict__ bsum) {
    __shared__ int s[256];
    int t = threadIdx.x;
    int v = (t < SCAN_NB) ? bsum[t] : 0;
    s[t] = v;
    __syncthreads();
    for (int o = 1; o < 256; o <<= 1) {
        int x = (t >= o) ? s[t - o] : 0;
        __syncthreads();
        s[t] += x;
        __syncthreads();
    }
    if (t < SCAN_NB) bsum[t] = (t == 0) ? 0 : s[t - 1];  // exclusive scan of block sums
}

__global__ __launch_bounds__(SCAN_B) void k_scan3(const int* __restrict__ deg,
                                                  const int* __restrict__ bsum,
                                                  int* __restrict__ offs,
                                                  float* __restrict__ norm,
                                                  int* __restrict__ cursor) {
    __shared__ int s[SCAN_B];
    int t = threadIdx.x;
    int i = blockIdx.x * SCAN_B + t;
    int v = (i < N_NODES) ? deg[i] : 0;
    s[t] = v;
    __syncthreads();
    for (int o = 1; o < SCAN_B; o <<= 1) {
        int x = (t >= o) ? s[t - o] : 0;
        __syncthreads();
        s[t] += x;
        __syncthreads();
    }
    if (i < N_NODES) {
        offs[i] = bsum[blockIdx.x] + s[t] - v;  // exclusive
        norm[i] = rsqrtf(fmaxf((float)v, 1.0f));
        cursor[i] = 0;                           // zero for k_fill (replaces memset)
    }
    if (blockIdx.x == 0 && t == 0) offs[N_NODES] = N_EDGES;
}

// ---------- 3. CSR bucket fill ----------
__global__ __launch_bounds__(256) void k_fill(const int* __restrict__ src,
                                              const int* __restrict__ dst,
                                              const int* __restrict__ offs,
                                              int* __restrict__ cursor,
                                              int* __restrict__ ssrc) {
    int i = blockIdx.x * 256 + threadIdx.x;
    if (i < N_EDGES) {
        int d = dst[i];
        int p = atomicAdd(&cursor[d], 1);
        ssrc[offs[d] + p] = src[i];
    }
}

// ---------- 4. featn = feat * norm[row] (float4 elementwise) ----------
__global__ __launch_bounds__(256) void k_featn(const float* __restrict__ feat,
                                               const float* __restrict__ norm,
                                               float* __restrict__ featn) {
    int idx = blockIdx.x * 256 + threadIdx.x;  // float4 index; F/4=32 per row
    int row = idx >> 5;
    float nv = norm[row];
    float4 v = ((const float4*)feat)[idx];
    v.x *= nv; v.y *= nv; v.z *= nv; v.w *= nv;
    ((float4*)featn)[idx] = v;
}

// ---------- 5. pack GRU weights for vectorized, coalesced Phase-C loads ----------
// wPa[k*128+j] = {w_ih[j][k], w_ih[j+128][k], w_ih[j+256][k], w_hh[j][k]}
// wPb[k*128+j] = {w_hh[j+128][k], w_hh[j+256][k]}
__global__ __launch_bounds__(256) void k_pack(const float* __restrict__ w_ih,
                                              const float* __restrict__ w_hh,
                                              float4* __restrict__ wPa,
                                              float2* __restrict__ wPb) {
    int idx = blockIdx.x * 256 + threadIdx.x;  // 0..16383
    int k = idx >> 7, j = idx & 127;
    float4 a;
    a.x = w_ih[j * 128 + k];
    a.y = w_ih[(j + 128) * 128 + k];
    a.z = w_ih[(j + 256) * 128 + k];
    a.w = w_hh[j * 128 + k];
    float2 b;
    b.x = w_hh[(j + 128) * 128 + k];
    b.y = w_hh[(j + 256) * 128 + k];
    wPa[idx] = a;
    wPb[idx] = b;
}

// ---------- 6. fused gather + rst-GEMM + GRU ----------
// 512 threads, ROWS=16, 4 rows/thread (rg in {0,4,8,12}), fused r/z chains.
// PRE=true : `fsrc` = featn; wPa_/wPb_ = packed weights.
// PRE=false: `fsrc` = raw feat (norm inline); wih_/whh_ = raw [384][128] weights.
#define ROWS 16
template <bool PRE>
__global__ __launch_bounds__(512, 4) void k_fused(
    const float* __restrict__ fsrc, const float* __restrict__ norm,
    const int* __restrict__ offs, const int* __restrict__ ssrc,
    const float* __restrict__ W, const float* __restrict__ bias,
    const float4* __restrict__ wPa_, const float2* __restrict__ wPb_,
    const float* __restrict__ wih_, const float* __restrict__ whh_,
    const float* __restrict__ b_ih, const float* __restrict__ b_hh,
    float* __restrict__ out) {
    __shared__ float sagg[ROWS][F];
    __shared__ float sfeat[ROWS][F];
    __shared__ float srst[ROWS][F];
    __shared__ float snorm[ROWS];

    int t = threadIdx.x;
    int row0 = blockIdx.x * ROWS;

    if (t < ROWS) snorm[t] = norm[row0 + t];
    // stage featn tile (512 float4 = exactly 1/thread, coalesced)
    {
        int r = t >> 5, c = t & 31;
        float4 f = ((const float4*)(fsrc + (size_t)(row0 + r) * F))[c];
        if (!PRE) {
            float nv = norm[row0 + r];
            f.x *= nv; f.y *= nv; f.z *= nv; f.w *= nv;
        }
        ((float4*)&sfeat[r][0])[c] = f;
    }

    // ---- Phase A: gather-sum featn[src] rows into sagg ----
    // 8 waves, 2 nodes/wave; half-wave per edge, float4/lane; 8 edges/iter
    int wave = t >> 6, lane = t & 63;
    int hf = lane >> 5, sub = lane & 31;
    for (int ln = wave; ln < ROWS; ln += 8) {
        int node = row0 + ln;
        int beg = offs[node], end = offs[node + 1];
        float4 acc = make_float4(0.f, 0.f, 0.f, 0.f);
        int e = beg;
        for (; e + 7 < end; e += 8) {
            int s0 = ssrc[e + 0 + hf];
            int s1 = ssrc[e + 2 + hf];
            int s2 = ssrc[e + 4 + hf];
            int s3 = ssrc[e + 6 + hf];
            float4 v0 = *(const float4*)(fsrc + (size_t)s0 * F + sub * 4);
            float4 v1 = *(const float4*)(fsrc + (size_t)s1 * F + sub * 4);
            float4 v2 = *(const float4*)(fsrc + (size_t)s2 * F + sub * 4);
            float4 v3 = *(const float4*)(fsrc + (size_t)s3 * F + sub * 4);
            if (PRE) {
                acc.x += (v0.x + v1.x) + (v2.x + v3.x);
                acc.y += (v0.y + v1.y) + (v2.y + v3.y);
                acc.z += (v0.z + v1.z) + (v2.z + v3.z);
                acc.w += (v0.w + v1.w) + (v2.w + v3.w);
            } else {
                float n0 = norm[s0], n1 = norm[s1], n2 = norm[s2], n3 = norm[s3];
                acc.x = fmaf(v0.x, n0, acc.x); acc.y = fmaf(v0.y, n0, acc.y);
                acc.z = fmaf(v0.z, n0, acc.z); acc.w = fmaf(v0.w, n0, acc.w);
                acc.x = fmaf(v1.x, n1, acc.x); acc.y = fmaf(v1.y, n1, acc.y);
                acc.z = fmaf(v1.z, n1, acc.z); acc.w = fmaf(v1.w, n1, acc.w);
                acc.x = fmaf(v2.x, n2, acc.x); acc.y = fmaf(v2.y, n2, acc.y);
                acc.z = fmaf(v2.z, n2, acc.z); acc.w = fmaf(v2.w, n2, acc.w);
                acc.x = fmaf(v3.x, n3, acc.x); acc.y = fmaf(v3.y, n3, acc.y);
                acc.z = fmaf(v3.z, n3, acc.z); acc.w = fmaf(v3.w, n3, acc.w);
            }
        }
        for (; e < end; e += 2) {  // remainder 0..7 edges (odd handled by guard)
            int edge = e + hf;
            if (edge < end) {
                int s0 = ssrc[edge];
                float4 v0 = *(const float4*)(fsrc + (size_t)s0 * F + sub * 4);
                float n0 = PRE ? 1.0f : norm[s0];
                acc.x = fmaf(v0.x, n0, acc.x); acc.y = fmaf(v0.y, n0, acc.y);
                acc.z = fmaf(v0.z, n0, acc.z); acc.w = fmaf(v0.w, n0, acc.w);
            }
        }
        acc.x += __shfl_xor(acc.x, 32, 64);
        acc.y += __shfl_xor(acc.y, 32, 64);
        acc.z += __shfl_xor(acc.z, 32, 64);
        acc.w += __shfl_xor(acc.w, 32, 64);
        if (hf == 0) *(float4*)&sagg[ln][sub * 4] = acc;
    }
    __syncthreads();

    // ---- Phase B: srst = (sagg @ W) * norm + bias (4 rows/thread) ----
    int j = t & 127;
    int rg = (t >> 7) * 4;  // 0, 4, 8, 12
    {
        float acc[4] = {0, 0, 0, 0};
        for (int k = 0; k < F; k += 4) {
            float w0 = W[(k + 0) * F + j];  // coalesced across lanes
            float w1 = W[(k + 1) * F + j];
            float w2 = W[(k + 2) * F + j];
            float w3 = W[(k + 3) * F + j];
#pragma unroll
            for (int r = 0; r < 4; ++r) {
                float4 a = *(const float4*)&sagg[rg + r][k];  // LDS broadcast
                acc[r] = fmaf(a.x, w0, acc[r]);
                acc[r] = fmaf(a.y, w1, acc[r]);
                acc[r] = fmaf(a.z, w2, acc[r]);
                acc[r] = fmaf(a.w, w3, acc[r]);
            }
        }
        float bj = bias[j];
#pragma unroll
        for (int r = 0; r < 4; ++r) {
            srst[rg + r][j] = acc[r] * snorm[rg + r] + bj;
        }
    }
    __syncthreads();

    // ---- Phase C: GRU gates, fused r/z chains, packed-weight loads ----
    float accr[4] = {0, 0, 0, 0};   // i_r + h_r
    float accz[4] = {0, 0, 0, 0};   // i_z + h_z
    float accin[4] = {0, 0, 0, 0};  // i_n
    float acchn[4] = {0, 0, 0, 0};  // h_n

    if (PRE) {
        const float4* pa = wPa_ + j;  // [k][j], advance 128/row
        const float2* pb = wPb_ + j;
        for (int k = 0; k < F; k += 4) {
            float4 A0 = pa[(k + 0) * 128];
            float4 A1 = pa[(k + 1) * 128];
            float4 A2 = pa[(k + 2) * 128];
            float4 A3 = pa[(k + 3) * 128];
            float2 B0 = pb[(k + 0) * 128];
            float2 B1 = pb[(k + 1) * 128];
            float2 B2 = pb[(k + 2) * 128];
            float2 B3 = pb[(k + 3) * 128];
            // A.x=wir A.y=wiz A.z=win A.w=whr ; B.x=whz B.y=whn
#pragma unroll
            for (int r = 0; r < 4; ++r) {
                float4 a = *(const float4*)&sfeat[rg + r][k];  // LDS broadcast
                float4 h = *(const float4*)&srst[rg + r][k];
                accr[r] = fmaf(a.x, A0.x, accr[r]); accr[r] = fmaf(h.x, A0.w, accr[r]);
                accr[r] = fmaf(a.y, A1.x, accr[r]); accr[r] = fmaf(h.y, A1.w, accr[r]);
                accr[r] = fmaf(a.z, A2.x, accr[r]); accr[r] = fmaf(h.z, A2.w, accr[r]);
                accr[r] = fmaf(a.w, A3.x, accr[r]); accr[r] = fmaf(h.w, A3.w, accr[r]);
                accz[r] = fmaf(a.x, A0.y, accz[r]); accz[r] = fmaf(h.x, B0.x, accz[r]);
                accz[r] = fmaf(a.y, A1.y, accz[r]); accz[r] = fmaf(h.y, B1.x, accz[r]);
                accz[r] = fmaf(a.z, A2.y, accz[r]); accz[r] = fmaf(h.z, B2.x, accz[r]);
                accz[r] = fmaf(a.w, A3.y, accz[r]); accz[r] = fmaf(h.w, B3.x, accz[r]);
                accin[r] = fmaf(a.x, A0.z, accin[r]); accin[r] = fmaf(a.y, A1.z, accin[r]);
                accin[r] = fmaf(a.z, A2.z, accin[r]); accin[r] = fmaf(a.w, A3.z, accin[r]);
                acchn[r] = fmaf(h.x, B0.y, acchn[r]); acchn[r] = fmaf(h.y, B1.y, acchn[r]);
                acchn[r] = fmaf(h.z, B2.y, acchn[r]); acchn[r] = fmaf(h.w, B3.y, acchn[r]);
            }
        }
    } else {
        // fallback: raw [384][128] row-major weight rows (uncoalesced but correct)
        const float* wirp = wih_ + (size_t)(j + 0) * F;
        const float* wizp = wih_ + (size_t)(j + 128) * F;
        const float* winp = wih_ + (size_t)(j + 256) * F;
        const float* whrp = whh_ + (size_t)(j + 0) * F;
        const float* whzp = whh_ + (size_t)(j + 128) * F;
        const float* whnp = whh_ + (size_t)(j + 256) * F;
        for (int k = 0; k < F; k += 4) {
            float4 bir = *(const float4*)(wirp + k);
            float4 biz = *(const float4*)(wizp + k);
            float4 bin = *(const float4*)(winp + k);
            float4 bhr = *(const float4*)(whrp + k);
            float4 bhz = *(const float4*)(whzp + k);
            float4 bhn = *(const float4*)(whnp + k);
#pragma unroll
            for (int r = 0; r < 4; ++r) {
                float4 a = *(const float4*)&sfeat[rg + r][k];
                float4 h = *(const float4*)&srst[rg + r][k];
                accr[r] = fmaf(a.x, bir.x, accr[r]); accr[r] = fmaf(h.x, bhr.x, accr[r]);
                accr[r] = fmaf(a.y, bir.y, accr[r]); accr[r] = fmaf(h.y, bhr.y, accr[r]);
                accr[r] = fmaf(a.z, bir.z, accr[r]); accr[r] = fmaf(h.z, bhr.z, accr[r]);
                accr[r] = fmaf(a.w, bir.w, accr[r]); accr[r] = fmaf(h.w, bhr.w, accr[r]);
                accz[r] = fmaf(a.x, biz.x, accz[r]); accz[r] = fmaf(h.x, bhz.x, accz[r]);
                accz[r] = fmaf(a.y, biz.y, accz[r]); accz[r] = fmaf(h.y, bhz.y, accz[r]);
                accz[r] = fmaf(a.z, biz.z, accz[r]); accz[r] = fmaf(h.z, bhz.z, accz[r]);
                accz[r] = fmaf(a.w, biz.w, accz[r]); accz[r] = fmaf(h.w, bhz.w, accz[r]);
                accin[r] = fmaf(a.x, bin.x, accin[r]); accin[r] = fmaf(a.y, bin.y, accin[r]);
                accin[r] = fmaf(a.z, bin.z, accin[r]); accin[r] = fmaf(a.w, bin.w, accin[r]);
                acchn[r] = fmaf(h.x, bhn.x, acchn[r]); acchn[r] = fmaf(h.y, bhn.y, acchn[r]);
                acchn[r] = fmaf(h.z, bhn.z, acchn[r]); acchn[r] = fmaf(h.w, bhn.w, acchn[r]);
            }
        }
    }

    float Brz = b_ih[j] + b_hh[j];
    float Bzz = b_ih[j + 128] + b_hh[j + 128];
    float Bin = b_ih[j + 256], Bhn = b_hh[j + 256];
#pragma unroll
    for (int r = 0; r < 4; ++r) {
        int row = row0 + rg + r;
        float rr = 1.0f / (1.0f + __expf(-(accr[r] + Brz)));
        float zz = 1.0f / (1.0f + __expf(-(accz[r] + Bzz)));
        float nn = tanhf(accin[r] + Bin + rr * (acchn[r] + Bhn));
        float rstv = srst[rg + r][j];
        out[(size_t)row * F + j] = (1.0f - zz) * nn + zz * rstv;
    }
}

extern "C" void kernel_launch(void* const* d_in, const int* in_sizes, int n_in,
                              void* d_out, int out_size, void* d_ws, size_t ws_size,
                              hipStream_t stream) {
    const float* feat   = (const float*)d_in[0];
    const float* weight = (const float*)d_in[1];
    const float* bias   = (const float*)d_in[2];
    const float* w_ih   = (const float*)d_in[3];
    const float* w_hh   = (const float*)d_in[4];
    const float* b_ih   = (const float*)d_in[5];
    const float* b_hh   = (const float*)d_in[6];
    const int*   src    = (const int*)d_in[7];
    const int*   dst    = (const int*)d_in[8];
    float* out = (float*)d_out;

    char* ws = (char*)d_ws;
    int*    deg    = (int*)(ws + 0);
    float*  norm   = (float*)(ws + 400000);
    int*    offs   = (int*)(ws + 800000);
    int*    cursor = (int*)(ws + 1200016);
    int*    ssrc   = (int*)(ws + 1600016);
    int*    bsum   = (int*)(ws + 8000016);
    float*  featn  = (float*)(ws + WS_FEATN_OFF);
    float4* wPa    = (float4*)(ws + WS_WPA_OFF);
    float2* wPb    = (float2*)(ws + WS_WPB_OFF);

    hipMemsetAsync(deg, 0, N_NODES * sizeof(int), stream);

    k_degree<<<(N_EDGES + 255) / 256, 256, 0, stream>>>(dst, deg);
    k_scan1<<<SCAN_NB, SCAN_B, 0, stream>>>(deg, bsum);
    k_scan2<<<1, 256, 0, stream>>>(bsum);
    k_scan3<<<SCAN_NB, SCAN_B, 0, stream>>>(deg, bsum, offs, norm, cursor);
    k_fill<<<(N_EDGES + 255) / 256, 256, 0, stream>>>(src, dst, offs, cursor, ssrc);

    if (ws_size >= WS_NEED_FULL) {
        k_pack<<<64, 256, 0, stream>>>(w_ih, w_hh, wPa, wPb);
        k_featn<<<(N_NODES * F / 4) / 256, 256, 0, stream>>>(feat, norm, featn);
        k_fused<true><<<N_NODES / ROWS, 512, 0, stream>>>(featn, norm, offs, ssrc,
                                                          weight, bias, wPa, wPb,
                                                          nullptr, nullptr,
                                                          b_ih, b_hh, out);
    } else {
        k_fused<false><<<N_NODES / ROWS, 512, 0, stream>>>(feat, norm, offs, ssrc,
                                                           weight, bias, nullptr, nullptr,
                                                           w_ih, w_hh,
                                                           b_ih, b_hh, out);
    }
}